// Round 2
// baseline (216.057 us; speedup 1.0000x reference)
//
#include <hip/hip_runtime.h>
#include <hip/hip_bf16.h>

// Problem constants
#define B_SZ 8
#define L_SZ 2048
#define DM   512
#define HIDC 1024            // complex hidden channels
#define NROW (B_SZ*L_SZ)     // 16384
#define NCOL (2*HIDC)        // 2048 (re || im)
#define LCH  128             // scan chunk length
#define NCH  (L_SZ/LCH)      // 16 chunks

typedef __attribute__((ext_vector_type(8))) short bf16x8;
typedef __attribute__((ext_vector_type(4))) float f32x4;

typedef __attribute__((address_space(1))) const void gvoid_t;
typedef __attribute__((address_space(3))) void lvoid_t;

__device__ __forceinline__ void gload_lds16(const void* g, void* l) {
  // async global->LDS, 16B per lane; LDS dest must be wave-uniform-base + lane*16
  __builtin_amdgcn_global_load_lds((gvoid_t*)g, (lvoid_t*)l, 16, 0, 0);
}

__device__ __forceinline__ unsigned short f2bf(float v) {
  return __builtin_bit_cast(unsigned short, __float2bfloat16(v));
}

// ---------------- prep kernels ----------------
__global__ void k_cvt_x(const float* __restrict__ x, unsigned short* __restrict__ xb) {
  long i = (long)blockIdx.x * 256 + threadIdx.x;   // 2,097,152 threads, 4 elems each
  float4 v = ((const float4*)x)[i];
  ushort4 o;
  o.x = f2bf(v.x); o.y = f2bf(v.y); o.z = f2bf(v.z); o.w = f2bf(v.w);
  ((ushort4*)xb)[i] = o;
}

// W1b[n][k], n<1024: gamma*W_in_r[n][k]; n>=1024: gamma*W_in_i[n-1024][k]. b1 = gamma*b.
__global__ void k_prep_w1(const float* __restrict__ Wr, const float* __restrict__ Wi,
                          const float* __restrict__ br, const float* __restrict__ bi,
                          const float* __restrict__ gamma_log,
                          unsigned short* __restrict__ W1b, float* __restrict__ b1) {
  long idx = (long)blockIdx.x * 256 + threadIdx.x; // 2048*512
  int n = (int)(idx >> 9), k = (int)(idx & 511);
  int d = n & (HIDC - 1);
  float g = __expf(gamma_log[d]);
  float w = (n < HIDC) ? Wr[(long)d * DM + k] : Wi[(long)d * DM + k];
  W1b[idx] = f2bf(g * w);
  if (k == 0) b1[n] = g * ((n < HIDC) ? br[d] : bi[d]);
}

// W2b[e][k], k<1024: W_out_r[e][k]; k>=1024: -W_out_i[e][k-1024]
__global__ void k_prep_w2(const float* __restrict__ Wor, const float* __restrict__ Woi,
                          unsigned short* __restrict__ W2b) {
  long idx = (long)blockIdx.x * 256 + threadIdx.x; // 512*2048
  int e = (int)(idx >> 11), k = (int)(idx & 2047);
  float w = (k < HIDC) ? Wor[(long)e * HIDC + k] : -Woi[(long)e * HIDC + (k - HIDC)];
  W2b[idx] = f2bf(w);
}

__global__ void k_prep_lam(const float* __restrict__ nu_log, const float* __restrict__ theta_log,
                           float* __restrict__ lam) {
  int d = blockIdx.x * 256 + threadIdx.x;   // 1024
  if (d >= HIDC) return;
  float nu = __expf(nu_log[d]);
  float th = __expf(theta_log[d]);
  float mag = __expf(-nu);
  lam[d]        = mag * cosf(th);
  lam[HIDC + d] = mag * sinf(th);
}

// ---------------- pipelined bf16 MFMA GEMM ----------------
// C[M][N] = A[M][K] * Bw[N][K]^T (+bias[col]) (+resid), BM=256 BN=128 BK=64,
// 8 waves (4Mx2N, per-wave 64x64 = 4x4 16x16x32 frags x 2 ksteps).
// Triple-buffered LDS (144KB), depth-2 tile prefetch, in-loop s_waitcnt vmcnt(6)
// (never 0 until the tail), raw s_barrier. T2 XOR-swizzle: LDS row = 128B,
// data slot s of row R stored at slot s^(R&7); applied on the pre-swizzled
// global source (gload_lds dest stays linear) and on the ds_read address.
//
// Correctness ledger:
//  - stage(t+2) -> buf((t+2)%3) = buf((t-1)%3): all ds_reads of tile t-1
//    completed (lgkm-waited before their MFMA uses) before the barrier that
//    ended iter t-1, which precedes this issue. No WAR race.
//  - end of iter t: outstanding VMEM = stage(t+1) [6 loads, issued iter t-1]
//    + stage(t+2) [6 loads, this iter, iff t+2<NT]. vmcnt(6) [or vmcnt(0) when
//    no stage(t+2)] guarantees stage(t+1) landed; s_barrier makes it global.
#define LT 6                     // gloads per tile: A 4 units + B 2 units
template<int OUT_BF16, int HAS_RESID>
__global__ __launch_bounds__(512, 2)
void gemm_pipe(const unsigned short* __restrict__ A, const unsigned short* __restrict__ Bw,
               void* __restrict__ C, const float* __restrict__ bias,
               const float* __restrict__ resid, int M, int N, int K) {
  extern __shared__ unsigned short lds[];
  unsigned short* As = lds;                 // 3 * 16384 ushorts (3 * 32KB)
  unsigned short* Bs = lds + 3 * 16384;     // 3 *  8192 ushorts (3 * 16KB)

  const int tid  = threadIdx.x;
  const int w    = tid >> 6, lane = tid & 63;
  const int wr   = w >> 1,   wc   = w & 1;   // 4 x 2 wave grid
  const int fr   = lane & 15, lq  = lane >> 4;

  // XCD-aware bijective swizzle (nwg % 8 == 0 for both call sites)
  const int gx   = M >> 8;                   // tiles along M
  const int nwg  = gridDim.x * gridDim.y;
  const int orig = blockIdx.x + blockIdx.y * gridDim.x;
  const int swz  = (orig & 7) * (nwg >> 3) + (orig >> 3);
  const long m0  = (long)(swz % gx) * 256;
  const long n0  = (long)(swz / gx) * 128;

  // ---- staging addresses (pre-swizzled global source, linear LDS dest) ----
  const int srow  = tid >> 3;                // 0..63 within a 64-row unit
  const int gslot = (tid & 7) ^ (srow & 7);  // swizzled source slot
  const unsigned short* Ag0 = A + (m0 + 0 * 64 + srow) * (long)K + gslot * 8;
  const unsigned short* Ag1 = A + (m0 + 1 * 64 + srow) * (long)K + gslot * 8;
  const unsigned short* Ag2 = A + (m0 + 2 * 64 + srow) * (long)K + gslot * 8;
  const unsigned short* Ag3 = A + (m0 + 3 * 64 + srow) * (long)K + gslot * 8;
  const unsigned short* Bg0 = Bw + (n0 + 0 * 64 + srow) * (long)K + gslot * 8;
  const unsigned short* Bg1 = Bw + (n0 + 1 * 64 + srow) * (long)K + gslot * 8;
  const int ldst = tid * 8;                  // ushort index, = lane*16B within wave

#define STAGE(t, b) {                                                   \
    long ko = (long)(t) * 64;                                           \
    gload_lds16(Ag0 + ko, &As[(b) * 16384 +     0 + ldst]);             \
    gload_lds16(Ag1 + ko, &As[(b) * 16384 +  4096 + ldst]);             \
    gload_lds16(Ag2 + ko, &As[(b) * 16384 +  8192 + ldst]);             \
    gload_lds16(Ag3 + ko, &As[(b) * 16384 + 12288 + ldst]);             \
    gload_lds16(Bg0 + ko, &Bs[(b) * 8192 +      0 + ldst]);             \
    gload_lds16(Bg1 + ko, &Bs[(b) * 8192 +   4096 + ldst]); }

  // ---- ds_read addresses (swizzled) ----
  const int xr    = fr & 7;
  const int sx0   = ((0 + lq) ^ xr) << 3;    // kstep 0 slot, in ushorts
  const int sx1   = ((4 + lq) ^ xr) << 3;    // kstep 1 slot
  const int baseA = (wr * 64 + fr) * 64;
  const int baseB = (wc * 64 + fr) * 64;

  f32x4 acc[4][4] = {};
  const int NT = K >> 6;

  STAGE(0, 0);
  STAGE(1, 1);
  asm volatile("s_waitcnt vmcnt(6)" ::: "memory");   // tile 0 landed
  __builtin_amdgcn_s_barrier();
  __builtin_amdgcn_sched_barrier(0);

  for (int t = 0; t < NT; ++t) {
    if (t + 2 < NT) STAGE(t + 2, (t + 2) % 3);

    const int cb = t % 3;
    const unsigned short* Ab = As + cb * 16384;
    const unsigned short* Bb = Bs + cb * 8192;
    bf16x8 fa[4][2], fb[4][2];
#pragma unroll
    for (int m = 0; m < 4; m++) {
      fa[m][0] = *(const bf16x8*)&Ab[baseA + m * 1024 + sx0];
      fa[m][1] = *(const bf16x8*)&Ab[baseA + m * 1024 + sx1];
    }
#pragma unroll
    for (int n = 0; n < 4; n++) {
      fb[n][0] = *(const bf16x8*)&Bb[baseB + n * 1024 + sx0];
      fb[n][1] = *(const bf16x8*)&Bb[baseB + n * 1024 + sx1];
    }

    __builtin_amdgcn_s_setprio(1);
#pragma unroll
    for (int s = 0; s < 2; s++)
#pragma unroll
      for (int m = 0; m < 4; m++)
#pragma unroll
        for (int n = 0; n < 4; n++)
          acc[m][n] = __builtin_amdgcn_mfma_f32_16x16x32_bf16(fa[m][s], fb[n][s], acc[m][n], 0, 0, 0);
    __builtin_amdgcn_s_setprio(0);

    if (t < NT - 1) {
      if (t + 2 < NT) { asm volatile("s_waitcnt vmcnt(6)" ::: "memory"); }
      else            { asm volatile("s_waitcnt vmcnt(0)" ::: "memory"); }
      __builtin_amdgcn_s_barrier();
      __builtin_amdgcn_sched_barrier(0);
    }
  }
#undef STAGE

  // epilogue: C/D layout col=lane&15, row=(lane>>4)*4+r (m89-verified)
  const int cr0 = lq * 4, cc = fr;
#pragma unroll
  for (int m = 0; m < 4; m++) {
#pragma unroll
    for (int n = 0; n < 4; n++) {
      long col = n0 + wc * 64 + n * 16 + cc;
      float bv = bias[col];
#pragma unroll
      for (int r = 0; r < 4; r++) {
        long row = m0 + wr * 64 + m * 16 + cr0 + r;
        float v = acc[m][n][r] + bv;
        if (HAS_RESID) v += resid[row * (long)N + col];
        if (OUT_BF16)
          ((unsigned short*)C)[row * (long)N + col] = f2bf(v);
        else
          ((float*)C)[row * (long)N + col] = v;
      }
    }
  }
}

// ---------------- chunked scan (3 passes), in-place on ubuf (bf16) ----------------
__global__ void k_scan_local(const __hip_bfloat16* __restrict__ u,
                             const float* __restrict__ lam,
                             const float* __restrict__ mask,
                             float* __restrict__ E) {
  int b = blockIdx.x, c = blockIdx.y, dg = blockIdx.z, t = threadIdx.x;
  int d = dg * 256 + t;
  float lr = lam[d], li = lam[HIDC + d];
  float hr = 0.f, hi = 0.f;
  const __hip_bfloat16* ur = u + ((long)(b * L_SZ + c * LCH)) * NCOL + d;
  const __hip_bfloat16* ui = ur + HIDC;
  const float* mrow = mask + b * L_SZ + c * LCH;
  for (int l = 0; l < LCH; l++) {
    float xr = __bfloat162float(ur[(long)l * NCOL]);
    float xi = __bfloat162float(ui[(long)l * NCOL]);
    float g = (l > 0) ? mrow[l - 1] : 0.f;
    float nr = xr + g * (lr * hr - li * hi);
    float ni = xi + g * (lr * hi + li * hr);
    hr = nr; hi = ni;
  }
  E[(((long)b * NCH + c) * 2) * HIDC + d]     = hr;
  E[(((long)b * NCH + c) * 2 + 1) * HIDC + d] = hi;
}

__global__ void k_scan_carry(const float* __restrict__ E, const float* __restrict__ lam,
                             float* __restrict__ P) {
  int idx = blockIdx.x * 256 + threadIdx.x;   // 8192 = B * HIDC
  int b = idx >> 10, d = idx & (HIDC - 1);
  float lr = lam[d], li = lam[HIDC + d];
  float ar = lr, ai = li;                     // lam^128 via 7 squarings
  for (int s = 0; s < 7; s++) { float nr = ar * ar - ai * ai; float ni = 2.f * ar * ai; ar = nr; ai = ni; }
  float pr = 0.f, pi = 0.f;
  for (int c = 0; c < NCH; c++) {
    P[(((long)b * NCH + c) * 2) * HIDC + d]     = pr;
    P[(((long)b * NCH + c) * 2 + 1) * HIDC + d] = pi;
    float er = E[(((long)b * NCH + c) * 2) * HIDC + d];
    float ei = E[(((long)b * NCH + c) * 2 + 1) * HIDC + d];
    float nr = er + ar * pr - ai * pi;
    float ni = ei + ar * pi + ai * pr;
    pr = nr; pi = ni;
  }
}

__global__ void k_scan_final(__hip_bfloat16* __restrict__ u,
                             const float* __restrict__ lam,
                             const float* __restrict__ mask,
                             const float* __restrict__ P) {
  int b = blockIdx.x, c = blockIdx.y, dg = blockIdx.z, t = threadIdx.x;
  int d = dg * 256 + t;
  float lr = lam[d], li = lam[HIDC + d];
  float hr = P[(((long)b * NCH + c) * 2) * HIDC + d];
  float hi = P[(((long)b * NCH + c) * 2 + 1) * HIDC + d];
  __hip_bfloat16* ur = u + ((long)(b * L_SZ + c * LCH)) * NCOL + d;
  __hip_bfloat16* ui = ur + HIDC;
  const float* mrow = mask + b * L_SZ + c * LCH;
  for (int l = 0; l < LCH; l++) {
    float xr = __bfloat162float(ur[(long)l * NCOL]);
    float xi = __bfloat162float(ui[(long)l * NCOL]);
    int gl = c * LCH + l;
    float g = (gl > 0) ? mrow[l - 1] : 0.f;
    float nr = xr + g * (lr * hr - li * hi);
    float ni = xi + g * (lr * hi + li * hr);
    hr = nr; hi = ni;
    ur[(long)l * NCOL] = __float2bfloat16(hr);
    ui[(long)l * NCOL] = __float2bfloat16(hi);
  }
}

// ---------------- LayerNorm over D=512, in place on d_out ----------------
__global__ __launch_bounds__(256) void k_ln(float* __restrict__ y,
                                            const float* __restrict__ lnw,
                                            const float* __restrict__ lnb) {
  int row = blockIdx.x, t = threadIdx.x;
  float2 v = ((const float2*)(y + (long)row * DM))[t];
  float s = v.x + v.y;
  float q = v.x * v.x + v.y * v.y;
  for (int off = 32; off; off >>= 1) { s += __shfl_down(s, off); q += __shfl_down(q, off); }
  __shared__ float ss[4], sq[4];
  int w = t >> 6, lane = t & 63;
  if (lane == 0) { ss[w] = s; sq[w] = q; }
  __syncthreads();
  if (t == 0) {
    float S = ss[0] + ss[1] + ss[2] + ss[3];
    float Q = sq[0] + sq[1] + sq[2] + sq[3];
    float mu = S / (float)DM;
    float var = Q / (float)DM - mu * mu;
    ss[0] = mu; sq[0] = rsqrtf(var + 1e-5f);
  }
  __syncthreads();
  float mu = ss[0], rstd = sq[0];
  float2 o;
  o.x = (v.x - mu) * rstd * lnw[2 * t]     + lnb[2 * t];
  o.y = (v.y - mu) * rstd * lnw[2 * t + 1] + lnb[2 * t + 1];
  ((float2*)(y + (long)row * DM))[t] = o;
}

// ---------------- launch ----------------
extern "C" void kernel_launch(void* const* d_in, const int* in_sizes, int n_in,
                              void* d_out, int out_size, void* d_ws, size_t ws_size,
                              hipStream_t stream) {
  (void)in_sizes; (void)n_in; (void)out_size; (void)ws_size;
  const float* x         = (const float*)d_in[0];
  const float* mask      = (const float*)d_in[1];
  const float* nu_log    = (const float*)d_in[2];
  const float* theta_log = (const float*)d_in[3];
  const float* gamma_log = (const float*)d_in[4];
  const float* W_in_r    = (const float*)d_in[5];
  const float* W_in_i    = (const float*)d_in[6];
  const float* b_in_r    = (const float*)d_in[7];
  const float* b_in_i    = (const float*)d_in[8];
  const float* W_out_r   = (const float*)d_in[9];
  const float* W_out_i   = (const float*)d_in[10];
  const float* b_out_r   = (const float*)d_in[11];
  const float* ln_w      = (const float*)d_in[13];
  const float* ln_b      = (const float*)d_in[14];

  char* ws = (char*)d_ws;
  unsigned short* ubuf = (unsigned short*)(ws);              // 67,108,864
  unsigned short* xb   = (unsigned short*)(ws + 67108864);   // 16,777,216
  unsigned short* W1b  = (unsigned short*)(ws + 83886080);   // 2,097,152
  unsigned short* W2b  = (unsigned short*)(ws + 85983232);   // 2,097,152
  float* b1   = (float*)(ws + 88080384);                     // 8,192
  float* lam  = (float*)(ws + 88088576);                     // 8,192
  float* Ebuf = (float*)(ws + 88096768);                     // 1,048,576
  float* Pbuf = (float*)(ws + 89145344);                     // 1,048,576

  const int LDS_BYTES = (3 * 16384 + 3 * 8192) * 2;          // 147456
  hipFuncSetAttribute((const void*)gemm_pipe<1, 0>,
                      hipFuncAttributeMaxDynamicSharedMemorySize, LDS_BYTES);
  hipFuncSetAttribute((const void*)gemm_pipe<0, 1>,
                      hipFuncAttributeMaxDynamicSharedMemorySize, LDS_BYTES);

  k_cvt_x  <<<8192, 256, 0, stream>>>(x, xb);
  k_prep_w1<<<4096, 256, 0, stream>>>(W_in_r, W_in_i, b_in_r, b_in_i, gamma_log, W1b, b1);
  k_prep_w2<<<4096, 256, 0, stream>>>(W_out_r, W_out_i, W2b);
  k_prep_lam<<<4, 256, 0, stream>>>(nu_log, theta_log, lam);

  // GEMM1: u = xb @ W1b^T + b1 -> bf16 ubuf [16384][2048]; grid 64x16=1024 WGs
  gemm_pipe<1, 0><<<dim3(NROW / 256, NCOL / 128), 512, LDS_BYTES, stream>>>(
      xb, W1b, (void*)ubuf, b1, nullptr, NROW, NCOL, DM);

  // chunked linear-recurrence scan, in place on ubuf
  k_scan_local<<<dim3(B_SZ, NCH, HIDC / 256), 256, 0, stream>>>(
      (const __hip_bfloat16*)ubuf, lam, mask, Ebuf);
  k_scan_carry<<<32, 256, 0, stream>>>(Ebuf, lam, Pbuf);
  k_scan_final<<<dim3(B_SZ, NCH, HIDC / 256), 256, 0, stream>>>(
      (__hip_bfloat16*)ubuf, lam, mask, Pbuf);

  // GEMM2: out = h @ W2b^T + b_out_r + x -> fp32 d_out [16384][512]; grid 64x4=256 WGs
  gemm_pipe<0, 1><<<dim3(NROW / 256, DM / 128), 512, LDS_BYTES, stream>>>(
      ubuf, W2b, d_out, b_out_r, x, NROW, DM, NCOL);

  // LayerNorm in place on d_out
  k_ln<<<NROW, 256, 0, stream>>>((float*)d_out, ln_w, ln_b);
}

// Round 3
// 203.895 us; speedup vs baseline: 1.0596x; 1.0596x over previous
//
#include <hip/hip_runtime.h>
#include <hip/hip_bf16.h>

// Problem constants
#define B_SZ 8
#define L_SZ 2048
#define DM   512
#define HIDC 1024            // complex hidden channels
#define NROW (B_SZ*L_SZ)     // 16384
#define NCOL (2*HIDC)        // 2048 (re || im)
#define LCH  128             // scan chunk length
#define NCH  (L_SZ/LCH)      // 16 chunks

typedef __attribute__((ext_vector_type(8))) short bf16x8;
typedef __attribute__((ext_vector_type(4))) float f32x4;

typedef __attribute__((address_space(1))) const void gvoid_t;
typedef __attribute__((address_space(3))) void lvoid_t;

__device__ __forceinline__ void gload_lds16(const void* g, void* l) {
  __builtin_amdgcn_global_load_lds((gvoid_t*)g, (lvoid_t*)l, 16, 0, 0);
}

__device__ __forceinline__ unsigned short f2bf(float v) {
  return __builtin_bit_cast(unsigned short, __float2bfloat16(v));
}
__device__ __forceinline__ float bf2f(unsigned short u) {
  return __bfloat162float(__builtin_bit_cast(__hip_bfloat16, u));
}

// ---------------- prep kernels ----------------
__global__ void k_cvt_x(const float* __restrict__ x, unsigned short* __restrict__ xb) {
  long i = (long)blockIdx.x * 256 + threadIdx.x;
  float4 v = ((const float4*)x)[i];
  ushort4 o;
  o.x = f2bf(v.x); o.y = f2bf(v.y); o.z = f2bf(v.z); o.w = f2bf(v.w);
  ((ushort4*)xb)[i] = o;
}

__global__ void k_prep_w1(const float* __restrict__ Wr, const float* __restrict__ Wi,
                          const float* __restrict__ br, const float* __restrict__ bi,
                          const float* __restrict__ gamma_log,
                          unsigned short* __restrict__ W1b, float* __restrict__ b1) {
  long idx = (long)blockIdx.x * 256 + threadIdx.x; // 2048*512
  int n = (int)(idx >> 9), k = (int)(idx & 511);
  int d = n & (HIDC - 1);
  float g = __expf(gamma_log[d]);
  float w = (n < HIDC) ? Wr[(long)d * DM + k] : Wi[(long)d * DM + k];
  W1b[idx] = f2bf(g * w);
  if (k == 0) b1[n] = g * ((n < HIDC) ? br[d] : bi[d]);
}

__global__ void k_prep_w2(const float* __restrict__ Wor, const float* __restrict__ Woi,
                          unsigned short* __restrict__ W2b) {
  long idx = (long)blockIdx.x * 256 + threadIdx.x; // 512*2048
  int e = (int)(idx >> 11), k = (int)(idx & 2047);
  float w = (k < HIDC) ? Wor[(long)e * HIDC + k] : -Woi[(long)e * HIDC + (k - HIDC)];
  W2b[idx] = f2bf(w);
}

__global__ void k_prep_lam(const float* __restrict__ nu_log, const float* __restrict__ theta_log,
                           float* __restrict__ lam) {
  int d = blockIdx.x * 256 + threadIdx.x;
  if (d >= HIDC) return;
  float nu = __expf(nu_log[d]);
  float th = __expf(theta_log[d]);
  float mag = __expf(-nu);
  lam[d]        = mag * cosf(th);
  lam[HIDC + d] = mag * sinf(th);
}

// ---------------- pipelined bf16 MFMA GEMM (v3) ----------------
// C[M][N] = A[M][K]*Bw[N][K]^T (+bias[col]) (+bf16 resid). BM=256 BN=128 BK=64,
// 256 threads = 4 waves (2M x 2N), per-wave 128x64 = 8x4 frags x 2 ksteps
// (balanced: 12 ds_read_b128 per 32 MFMA per kstep).
// Triple-buffered LDS (144KB), depth-2 prefetch, in-loop s_waitcnt vmcnt(12).
// T2 XOR swizzle: 128B rows, 16B slot s of row r stored at s^(r&7); applied on
// pre-swizzled global source (linear gload_lds dest) and on ds_read address.
// XCD 2-D blocking: XCD x owns m-tiles [x*gx/8,(x+1)*gx/8) x ALL n, n-fastest,
// so the A band and full B stay L2-resident per XCD.
//
// Race ledger (unchanged from R1, which passed):
//  - STAGE(t+2) overwrites buf((t-1)%3); all ds_reads of tile t-1 completed
//    (lgkm-waited before their MFMA consumers) before the barrier ending iter
//    t-1, which precedes this issue.
//  - end of iter t: outstanding = stage(t+1)[12] + stage(t+2)[12 iff issued].
//    vmcnt(12) (or 0 when t+2>=NT) guarantees stage(t+1) landed; s_barrier
//    publishes it.
template<int OUT_BF16, int HAS_RESID, int LGY>
__global__ __launch_bounds__(256, 1)
void gemm_pipe(const unsigned short* __restrict__ A, const unsigned short* __restrict__ Bw,
               void* __restrict__ C, const float* __restrict__ bias,
               const unsigned short* __restrict__ resid, int M, int N, int K) {
  extern __shared__ unsigned short lds[];
  unsigned short* As = lds;               // 3 * 16384 ushorts
  unsigned short* Bs = lds + 3 * 16384;   // 3 *  8192 ushorts

  const int tid  = threadIdx.x;
  const int w    = tid >> 6, lane = tid & 63;
  const int wr   = w >> 1,   wc   = w & 1;    // 2 x 2 wave grid
  const int fr   = lane & 15, lq  = lane >> 4;

  // XCD 2-D blocking (blockIdx.x % 8 assumed = XCD; perf heuristic only)
  const int gx   = M >> 8;                    // m-tiles (64)
  const int xcd  = blockIdx.x & 7;
  const int idx  = blockIdx.x >> 3;           // [0, (gx/8) << LGY)
  const int mt   = xcd * (gx >> 3) + (idx >> LGY);
  const int nt   = idx & ((1 << LGY) - 1);
  const long m0  = (long)mt * 256;
  const long n0  = (long)nt * 128;

  // ---- staging addressing: 256 thr * 16B = 4KB = 32 rows(128B)/call ----
  const int srow  = tid >> 3;                 // 0..31
  const int gslot = (tid & 7) ^ (srow & 7);   // pre-swizzled source slot
  const unsigned short* Agp = A  + (m0 + srow) * (long)K + gslot * 8;
  const unsigned short* Bgp = Bw + (n0 + srow) * (long)K + gslot * 8;
  const int ldst = tid * 8;                   // ushort idx = byte tid*16

#define STAGE(t, b) {                                                        \
    long ko = (long)(t) * 64;                                                \
    _Pragma("unroll")                                                        \
    for (int u = 0; u < 8; u++)                                              \
      gload_lds16(Agp + ko + (long)(u * 32) * K,                             \
                  &As[(b) * 16384 + u * 2048 + ldst]);                       \
    _Pragma("unroll")                                                        \
    for (int u = 0; u < 4; u++)                                              \
      gload_lds16(Bgp + ko + (long)(u * 32) * K,                             \
                  &Bs[(b) * 8192 + u * 2048 + ldst]); }

  // ---- ds_read addresses (swizzled): slot' = (ks*4+lq)^(fr&7) ----
  const int xr  = fr & 7;
  const int sx0 = ((0 + lq) ^ xr) << 3;       // kstep 0, ushorts
  const int sx1 = ((4 + lq) ^ xr) << 3;       // kstep 1

  f32x4 acc[8][4] = {};
  const int NT = K >> 6;

  STAGE(0, 0);
  STAGE(1, 1);
  asm volatile("s_waitcnt vmcnt(12)" ::: "memory");
  __builtin_amdgcn_s_barrier();
  __builtin_amdgcn_sched_barrier(0);

  int cb = 0, bt2 = 2;
  for (int t = 0; t < NT; ++t) {
    if (t + 2 < NT) STAGE(t + 2, bt2);

    const unsigned short* Ab = As + cb * 16384;
    const unsigned short* Bb = Bs + cb * 8192;
#pragma unroll
    for (int s = 0; s < 2; ++s) {
      const int sx = s ? sx1 : sx0;
      bf16x8 fa[8], fb[4];
#pragma unroll
      for (int m = 0; m < 8; m++)
        fa[m] = *(const bf16x8*)&Ab[(wr * 128 + m * 16 + fr) * 64 + sx];
#pragma unroll
      for (int n = 0; n < 4; n++)
        fb[n] = *(const bf16x8*)&Bb[(wc * 64 + n * 16 + fr) * 64 + sx];
      __builtin_amdgcn_s_setprio(1);
#pragma unroll
      for (int m = 0; m < 8; m++)
#pragma unroll
        for (int n = 0; n < 4; n++)
          acc[m][n] = __builtin_amdgcn_mfma_f32_16x16x32_bf16(fa[m], fb[n], acc[m][n], 0, 0, 0);
      __builtin_amdgcn_s_setprio(0);
    }

    if (t < NT - 1) {
      if (t + 2 < NT) { asm volatile("s_waitcnt vmcnt(12)" ::: "memory"); }
      else            { asm volatile("s_waitcnt vmcnt(0)"  ::: "memory"); }
      __builtin_amdgcn_s_barrier();
      __builtin_amdgcn_sched_barrier(0);
    }
    cb  = (cb  == 2) ? 0 : cb + 1;
    bt2 = (bt2 == 2) ? 0 : bt2 + 1;
  }
#undef STAGE

  // epilogue: C/D layout col=lane&15, row=(lane>>4)*4+r (m89-verified)
  const int cr0 = lq * 4, cc = fr;
#pragma unroll
  for (int m = 0; m < 8; m++) {
#pragma unroll
    for (int n = 0; n < 4; n++) {
      long col = n0 + wc * 64 + n * 16 + cc;
      float bv = bias[col];
#pragma unroll
      for (int r = 0; r < 4; r++) {
        long row = m0 + wr * 128 + m * 16 + cr0 + r;
        float v = acc[m][n][r] + bv;
        if (HAS_RESID) v += bf2f(resid[row * (long)N + col]);
        if (OUT_BF16)
          ((unsigned short*)C)[row * (long)N + col] = f2bf(v);
        else
          ((float*)C)[row * (long)N + col] = v;
      }
    }
  }
}

// ---------------- chunked scan (3 passes), in-place on ubuf (bf16) ----------------
__global__ void k_scan_local(const __hip_bfloat16* __restrict__ u,
                             const float* __restrict__ lam,
                             const float* __restrict__ mask,
                             float* __restrict__ E) {
  int b = blockIdx.x, c = blockIdx.y, dg = blockIdx.z, t = threadIdx.x;
  int d = dg * 256 + t;
  float lr = lam[d], li = lam[HIDC + d];
  float hr = 0.f, hi = 0.f;
  const __hip_bfloat16* ur = u + ((long)(b * L_SZ + c * LCH)) * NCOL + d;
  const __hip_bfloat16* ui = ur + HIDC;
  const float* mrow = mask + b * L_SZ + c * LCH;
  for (int l = 0; l < LCH; l++) {
    float xr = __bfloat162float(ur[(long)l * NCOL]);
    float xi = __bfloat162float(ui[(long)l * NCOL]);
    float g = (l > 0) ? mrow[l - 1] : 0.f;
    float nr = xr + g * (lr * hr - li * hi);
    float ni = xi + g * (lr * hi + li * hr);
    hr = nr; hi = ni;
  }
  E[(((long)b * NCH + c) * 2) * HIDC + d]     = hr;
  E[(((long)b * NCH + c) * 2 + 1) * HIDC + d] = hi;
}

__global__ void k_scan_carry(const float* __restrict__ E, const float* __restrict__ lam,
                             float* __restrict__ P) {
  int idx = blockIdx.x * 256 + threadIdx.x;   // 8192 = B * HIDC
  int b = idx >> 10, d = idx & (HIDC - 1);
  float lr = lam[d], li = lam[HIDC + d];
  float ar = lr, ai = li;                     // lam^128 via 7 squarings
  for (int s = 0; s < 7; s++) { float nr = ar * ar - ai * ai; float ni = 2.f * ar * ai; ar = nr; ai = ni; }
  float pr = 0.f, pi = 0.f;
  for (int c = 0; c < NCH; c++) {
    P[(((long)b * NCH + c) * 2) * HIDC + d]     = pr;
    P[(((long)b * NCH + c) * 2 + 1) * HIDC + d] = pi;
    float er = E[(((long)b * NCH + c) * 2) * HIDC + d];
    float ei = E[(((long)b * NCH + c) * 2 + 1) * HIDC + d];
    float nr = er + ar * pr - ai * pi;
    float ni = ei + ar * pi + ai * pr;
    pr = nr; pi = ni;
  }
}

__global__ void k_scan_final(__hip_bfloat16* __restrict__ u,
                             const float* __restrict__ lam,
                             const float* __restrict__ mask,
                             const float* __restrict__ P) {
  int b = blockIdx.x, c = blockIdx.y, dg = blockIdx.z, t = threadIdx.x;
  int d = dg * 256 + t;
  float lr = lam[d], li = lam[HIDC + d];
  float hr = P[(((long)b * NCH + c) * 2) * HIDC + d];
  float hi = P[(((long)b * NCH + c) * 2 + 1) * HIDC + d];
  __hip_bfloat16* ur = u + ((long)(b * L_SZ + c * LCH)) * NCOL + d;
  __hip_bfloat16* ui = ur + HIDC;
  const float* mrow = mask + b * L_SZ + c * LCH;
  for (int l = 0; l < LCH; l++) {
    float xr = __bfloat162float(ur[(long)l * NCOL]);
    float xi = __bfloat162float(ui[(long)l * NCOL]);
    int gl = c * LCH + l;
    float g = (gl > 0) ? mrow[l - 1] : 0.f;
    float nr = xr + g * (lr * hr - li * hi);
    float ni = xi + g * (lr * hi + li * hr);
    hr = nr; hi = ni;
    ur[(long)l * NCOL] = __float2bfloat16(hr);
    ui[(long)l * NCOL] = __float2bfloat16(hi);
  }
}

// ---------------- LayerNorm over D=512, in place on d_out ----------------
__global__ __launch_bounds__(256) void k_ln(float* __restrict__ y,
                                            const float* __restrict__ lnw,
                                            const float* __restrict__ lnb) {
  int row = blockIdx.x, t = threadIdx.x;
  float2 v = ((const float2*)(y + (long)row * DM))[t];
  float s = v.x + v.y;
  float q = v.x * v.x + v.y * v.y;
  for (int off = 32; off; off >>= 1) { s += __shfl_down(s, off); q += __shfl_down(q, off); }
  __shared__ float ss[4], sq[4];
  int w = t >> 6, lane = t & 63;
  if (lane == 0) { ss[w] = s; sq[w] = q; }
  __syncthreads();
  if (t == 0) {
    float S = ss[0] + ss[1] + ss[2] + ss[3];
    float Q = sq[0] + sq[1] + sq[2] + sq[3];
    float mu = S / (float)DM;
    float var = Q / (float)DM - mu * mu;
    ss[0] = mu; sq[0] = rsqrtf(var + 1e-5f);
  }
  __syncthreads();
  float mu = ss[0], rstd = sq[0];
  float2 o;
  o.x = (v.x - mu) * rstd * lnw[2 * t]     + lnb[2 * t];
  o.y = (v.y - mu) * rstd * lnw[2 * t + 1] + lnb[2 * t + 1];
  ((float2*)(y + (long)row * DM))[t] = o;
}

// ---------------- launch ----------------
extern "C" void kernel_launch(void* const* d_in, const int* in_sizes, int n_in,
                              void* d_out, int out_size, void* d_ws, size_t ws_size,
                              hipStream_t stream) {
  (void)in_sizes; (void)n_in; (void)out_size; (void)ws_size;
  const float* x         = (const float*)d_in[0];
  const float* mask      = (const float*)d_in[1];
  const float* nu_log    = (const float*)d_in[2];
  const float* theta_log = (const float*)d_in[3];
  const float* gamma_log = (const float*)d_in[4];
  const float* W_in_r    = (const float*)d_in[5];
  const float* W_in_i    = (const float*)d_in[6];
  const float* b_in_r    = (const float*)d_in[7];
  const float* b_in_i    = (const float*)d_in[8];
  const float* W_out_r   = (const float*)d_in[9];
  const float* W_out_i   = (const float*)d_in[10];
  const float* b_out_r   = (const float*)d_in[11];
  const float* ln_w      = (const float*)d_in[13];
  const float* ln_b      = (const float*)d_in[14];

  char* ws = (char*)d_ws;
  unsigned short* ubuf = (unsigned short*)(ws);              // 67,108,864
  unsigned short* xb   = (unsigned short*)(ws + 67108864);   // 16,777,216 (wait: 32MB? no: 16384*512*2 = 16 MB)
  unsigned short* W1b  = (unsigned short*)(ws + 83886080);   // 2,097,152
  unsigned short* W2b  = (unsigned short*)(ws + 85983232);   // 2,097,152
  float* b1   = (float*)(ws + 88080384);                     // 8,192
  float* lam  = (float*)(ws + 88088576);                     // 8,192
  float* Ebuf = (float*)(ws + 88096768);                     // 1,048,576
  float* Pbuf = (float*)(ws + 89145344);                     // 1,048,576

  const int LDS_BYTES = 3 * (16384 + 8192) * 2;              // 147456
  hipFuncSetAttribute((const void*)gemm_pipe<1, 0, 4>,
                      hipFuncAttributeMaxDynamicSharedMemorySize, LDS_BYTES);
  hipFuncSetAttribute((const void*)gemm_pipe<0, 1, 2>,
                      hipFuncAttributeMaxDynamicSharedMemorySize, LDS_BYTES);

  k_cvt_x  <<<8192, 256, 0, stream>>>(x, xb);
  k_prep_w1<<<4096, 256, 0, stream>>>(W_in_r, W_in_i, b_in_r, b_in_i, gamma_log, W1b, b1);
  k_prep_w2<<<4096, 256, 0, stream>>>(W_out_r, W_out_i, W2b);
  k_prep_lam<<<4, 256, 0, stream>>>(nu_log, theta_log, lam);

  // GEMM1: u = xb @ W1b^T + b1 -> bf16 ubuf [16384][2048]; 1024 WGs (gy=16)
  gemm_pipe<1, 0, 4><<<1024, 256, LDS_BYTES, stream>>>(
      xb, W1b, (void*)ubuf, b1, nullptr, NROW, NCOL, DM);

  // chunked linear-recurrence scan, in place on ubuf
  k_scan_local<<<dim3(B_SZ, NCH, HIDC / 256), 256, 0, stream>>>(
      (const __hip_bfloat16*)ubuf, lam, mask, Ebuf);
  k_scan_carry<<<32, 256, 0, stream>>>(Ebuf, lam, Pbuf);
  k_scan_final<<<dim3(B_SZ, NCH, HIDC / 256), 256, 0, stream>>>(
      (__hip_bfloat16*)ubuf, lam, mask, Pbuf);

  // GEMM2: out = h @ W2b^T + b_out_r + xb -> fp32 d_out [16384][512]; 256 WGs (gy=4)
  gemm_pipe<0, 1, 2><<<256, 256, LDS_BYTES, stream>>>(
      ubuf, W2b, d_out, b_out_r, xb, NROW, DM, NCOL);

  // LayerNorm in place on d_out
  k_ln<<<NROW, 256, 0, stream>>>((float*)d_out, ln_w, ln_b);
}

// Round 4
// 192.991 us; speedup vs baseline: 1.1195x; 1.0565x over previous
//
#include <hip/hip_runtime.h>
#include <hip/hip_bf16.h>

// Problem constants
#define B_SZ 8
#define L_SZ 2048
#define DM   512
#define HIDC 1024            // complex hidden channels
#define NROW (B_SZ*L_SZ)     // 16384
#define NCOL (2*HIDC)        // 2048 (re || im)
#define LCH  128             // scan chunk length
#define NCH  (L_SZ/LCH)      // 16 chunks

typedef __attribute__((ext_vector_type(8))) short bf16x8;
typedef __attribute__((ext_vector_type(4))) float f32x4;

typedef __attribute__((address_space(1))) const void gvoid_t;
typedef __attribute__((address_space(3))) void lvoid_t;

__device__ __forceinline__ void gload_lds16(const void* g, void* l) {
  __builtin_amdgcn_global_load_lds((gvoid_t*)g, (lvoid_t*)l, 16, 0, 0);
}

__device__ __forceinline__ unsigned short f2bf(float v) {
  return __builtin_bit_cast(unsigned short, __float2bfloat16(v));
}
__device__ __forceinline__ float bf2f(unsigned short u) {
  return __bfloat162float(__builtin_bit_cast(__hip_bfloat16, u));
}

// ---------------- prep kernels ----------------
__global__ void k_cvt_x(const float* __restrict__ x, unsigned short* __restrict__ xb) {
  long i = (long)blockIdx.x * 256 + threadIdx.x;
  float4 v = ((const float4*)x)[i];
  ushort4 o;
  o.x = f2bf(v.x); o.y = f2bf(v.y); o.z = f2bf(v.z); o.w = f2bf(v.w);
  ((ushort4*)xb)[i] = o;
}

__global__ void k_prep_w1(const float* __restrict__ Wr, const float* __restrict__ Wi,
                          const float* __restrict__ br, const float* __restrict__ bi,
                          const float* __restrict__ gamma_log,
                          unsigned short* __restrict__ W1b, float* __restrict__ b1) {
  long idx = (long)blockIdx.x * 256 + threadIdx.x; // 2048*512
  int n = (int)(idx >> 9), k = (int)(idx & 511);
  int d = n & (HIDC - 1);
  float g = __expf(gamma_log[d]);
  float w = (n < HIDC) ? Wr[(long)d * DM + k] : Wi[(long)d * DM + k];
  W1b[idx] = f2bf(g * w);
  if (k == 0) b1[n] = g * ((n < HIDC) ? br[d] : bi[d]);
}

__global__ void k_prep_w2(const float* __restrict__ Wor, const float* __restrict__ Woi,
                          unsigned short* __restrict__ W2b) {
  long idx = (long)blockIdx.x * 256 + threadIdx.x; // 512*2048
  int e = (int)(idx >> 11), k = (int)(idx & 2047);
  float w = (k < HIDC) ? Wor[(long)e * HIDC + k] : -Woi[(long)e * HIDC + (k - HIDC)];
  W2b[idx] = f2bf(w);
}

__global__ void k_prep_lam(const float* __restrict__ nu_log, const float* __restrict__ theta_log,
                           float* __restrict__ lam) {
  int d = blockIdx.x * 256 + threadIdx.x;
  if (d >= HIDC) return;
  float nu = __expf(nu_log[d]);
  float th = __expf(theta_log[d]);
  float mag = __expf(-nu);
  lam[d]        = mag * cosf(th);
  lam[HIDC + d] = mag * sinf(th);
}

// ---------------- pipelined bf16 MFMA GEMM (v4) ----------------
// C[M][N] = A[M][K]*Bw[N][K]^T (+bias[col]) (+bf16 resid).
// BM = MF*32, BN = 128, BK = 32. 256 threads = 4 waves (2M x 2N); per-wave
// MF x 4 frags of 16x16x32 (one kstep per tile). Triple-buffered LDS
// (3*(BM+128)*64 B = 72KB @ MF=8, 48KB @ MF=4) -> 2 blocks/CU, 2 waves/SIMD.
// Depth-2 prefetch; in-loop wait = counted vmcnt(LT), LT = loads/stage.
// T2 swizzle for 64B rows (4x16B slots): slot' = slot ^ (row&3), applied to the
// pre-swizzled global source (linear gload_lds dest) and the ds_read address.
// Bank check: wave b128 reads spread 8 lanes per bank-quad = conflict floor.
// XCD 2-D blocking: XCD owns a contiguous m-band x all n, n-fastest.
//
// Race ledger (same skeleton as R1/R3, both passed):
//  - STAGE(t+2) overwrites buf((t-1)%3); tile t-1's ds_reads completed
//    (lgkm-waited before MFMA consumers) before the barrier ending iter t-1.
//  - end of iter t: outstanding = stage(t+1)[LT] + stage(t+2)[LT iff issued].
//    vmcnt(LT) (or 0 when none issued) => stage(t+1) landed; s_barrier
//    publishes it.
template<int MF, int OUT_BF16, int HAS_RESID, int LGY>
__global__ __launch_bounds__(256, 2)
void gemm_pipe(const unsigned short* __restrict__ A, const unsigned short* __restrict__ Bw,
               void* __restrict__ C, const float* __restrict__ bias,
               const unsigned short* __restrict__ resid, int M, int N, int K) {
  constexpr int BM     = MF * 32;
  constexpr int AUNITS = MF / 2;        // 4KB staging units per A tile
  constexpr int LT     = AUNITS + 2;    // gloads per stage
  constexpr int ABUF   = BM * 32;       // ushorts per A buffer
  constexpr int BBUF   = 128 * 32;

  extern __shared__ unsigned short lds[];
  unsigned short* As = lds;             // 3 * ABUF
  unsigned short* Bs = lds + 3 * ABUF;  // 3 * BBUF

  const int tid  = threadIdx.x;
  const int w    = tid >> 6, lane = tid & 63;
  const int wr   = w >> 1,   wc   = w & 1;    // 2 x 2 wave grid
  const int fr   = lane & 15, lq  = lane >> 4;

  // XCD 2-D blocking (blockIdx.x % 8 assumed = XCD; perf heuristic only)
  const int gx   = M / BM;
  const int xcd  = blockIdx.x & 7;
  const int idx  = blockIdx.x >> 3;
  const int mt   = xcd * (gx >> 3) + (idx >> LGY);
  const int nt   = idx & ((1 << LGY) - 1);
  const long m0  = (long)mt * BM;
  const long n0  = (long)nt * 128;

  // ---- staging: 64B rows, 4 threads/row; 256 thr * 16B = 64 rows per unit ----
  const int srow  = tid >> 2;                 // 0..63
  const int gslot = (tid & 3) ^ (srow & 3);   // pre-swizzled source slot
  const unsigned short* Agp = A  + (m0 + srow) * (long)K + gslot * 8;
  const unsigned short* Bgp = Bw + (n0 + srow) * (long)K + gslot * 8;
  const int ldst = tid * 8;

#define STAGE(t, b) {                                                        \
    long ko = (long)(t) * 32;                                                \
    _Pragma("unroll")                                                        \
    for (int u = 0; u < AUNITS; u++)                                         \
      gload_lds16(Agp + ko + (long)(u * 64) * K,                             \
                  &As[(b) * ABUF + u * 2048 + ldst]);                        \
    gload_lds16(Bgp + ko,                  &Bs[(b) * BBUF +        ldst]);   \
    gload_lds16(Bgp + ko + (long)64 * K,   &Bs[(b) * BBUF + 2048 + ldst]); }

  // ---- ds_read: row r slot (lq ^ (r&3)), ushort offset r*32 + slot*8 ----
  const int sx = (lq ^ (fr & 3)) << 3;

  f32x4 acc[MF][4] = {};
  const int NT = K >> 5;

  STAGE(0, 0);
  STAGE(1, 1);
  if constexpr (LT == 6) asm volatile("s_waitcnt vmcnt(6)" ::: "memory");
  else                   asm volatile("s_waitcnt vmcnt(4)" ::: "memory");
  __builtin_amdgcn_s_barrier();
  __builtin_amdgcn_sched_barrier(0);

  int cb = 0, bt2 = 2;
  for (int t = 0; t < NT; ++t) {
    if (t + 2 < NT) STAGE(t + 2, bt2);

    const unsigned short* Ab = As + cb * ABUF;
    const unsigned short* Bb = Bs + cb * BBUF;
    bf16x8 fa[MF], fb[4];
#pragma unroll
    for (int m = 0; m < MF; m++)
      fa[m] = *(const bf16x8*)&Ab[(wr * (MF * 16) + m * 16 + fr) * 32 + sx];
#pragma unroll
    for (int n = 0; n < 4; n++)
      fb[n] = *(const bf16x8*)&Bb[(wc * 64 + n * 16 + fr) * 32 + sx];
    __builtin_amdgcn_s_setprio(1);
#pragma unroll
    for (int m = 0; m < MF; m++)
#pragma unroll
      for (int n = 0; n < 4; n++)
        acc[m][n] = __builtin_amdgcn_mfma_f32_16x16x32_bf16(fa[m], fb[n], acc[m][n], 0, 0, 0);
    __builtin_amdgcn_s_setprio(0);

    if (t < NT - 1) {
      if (t + 2 < NT) {
        if constexpr (LT == 6) asm volatile("s_waitcnt vmcnt(6)" ::: "memory");
        else                   asm volatile("s_waitcnt vmcnt(4)" ::: "memory");
      } else {
        asm volatile("s_waitcnt vmcnt(0)" ::: "memory");
      }
      __builtin_amdgcn_s_barrier();
      __builtin_amdgcn_sched_barrier(0);
    }
    cb  = (cb  == 2) ? 0 : cb + 1;
    bt2 = (bt2 == 2) ? 0 : bt2 + 1;
  }
#undef STAGE

  // epilogue: C/D layout col=lane&15, row=(lane>>4)*4+r (m89-verified)
  const int cr0 = lq * 4, cc = fr;
#pragma unroll
  for (int m = 0; m < MF; m++) {
#pragma unroll
    for (int n = 0; n < 4; n++) {
      long col = n0 + wc * 64 + n * 16 + cc;
      float bv = bias[col];
#pragma unroll
      for (int r = 0; r < 4; r++) {
        long row = m0 + wr * (MF * 16) + m * 16 + cr0 + r;
        float v = acc[m][n][r] + bv;
        if (HAS_RESID) v += bf2f(resid[row * (long)N + col]);
        if (OUT_BF16)
          ((unsigned short*)C)[row * (long)N + col] = f2bf(v);
        else
          ((float*)C)[row * (long)N + col] = v;
      }
    }
  }
}

// ---------------- chunked scan (3 passes), in-place on ubuf (bf16) ----------------
__global__ void k_scan_local(const __hip_bfloat16* __restrict__ u,
                             const float* __restrict__ lam,
                             const float* __restrict__ mask,
                             float* __restrict__ E) {
  int b = blockIdx.x, c = blockIdx.y, dg = blockIdx.z, t = threadIdx.x;
  int d = dg * 256 + t;
  float lr = lam[d], li = lam[HIDC + d];
  float hr = 0.f, hi = 0.f;
  const __hip_bfloat16* ur = u + ((long)(b * L_SZ + c * LCH)) * NCOL + d;
  const __hip_bfloat16* ui = ur + HIDC;
  const float* mrow = mask + b * L_SZ + c * LCH;
  for (int l = 0; l < LCH; l++) {
    float xr = __bfloat162float(ur[(long)l * NCOL]);
    float xi = __bfloat162float(ui[(long)l * NCOL]);
    float g = (l > 0) ? mrow[l - 1] : 0.f;
    float nr = xr + g * (lr * hr - li * hi);
    float ni = xi + g * (lr * hi + li * hr);
    hr = nr; hi = ni;
  }
  E[(((long)b * NCH + c) * 2) * HIDC + d]     = hr;
  E[(((long)b * NCH + c) * 2 + 1) * HIDC + d] = hi;
}

__global__ void k_scan_carry(const float* __restrict__ E, const float* __restrict__ lam,
                             float* __restrict__ P) {
  int idx = blockIdx.x * 256 + threadIdx.x;   // 8192 = B * HIDC
  int b = idx >> 10, d = idx & (HIDC - 1);
  float lr = lam[d], li = lam[HIDC + d];
  float ar = lr, ai = li;                     // lam^128 via 7 squarings
  for (int s = 0; s < 7; s++) { float nr = ar * ar - ai * ai; float ni = 2.f * ar * ai; ar = nr; ai = ni; }
  float pr = 0.f, pi = 0.f;
  for (int c = 0; c < NCH; c++) {
    P[(((long)b * NCH + c) * 2) * HIDC + d]     = pr;
    P[(((long)b * NCH + c) * 2 + 1) * HIDC + d] = pi;
    float er = E[(((long)b * NCH + c) * 2) * HIDC + d];
    float ei = E[(((long)b * NCH + c) * 2 + 1) * HIDC + d];
    float nr = er + ar * pr - ai * pi;
    float ni = ei + ar * pi + ai * pr;
    pr = nr; pi = ni;
  }
}

__global__ void k_scan_final(__hip_bfloat16* __restrict__ u,
                             const float* __restrict__ lam,
                             const float* __restrict__ mask,
                             const float* __restrict__ P) {
  int b = blockIdx.x, c = blockIdx.y, dg = blockIdx.z, t = threadIdx.x;
  int d = dg * 256 + t;
  float lr = lam[d], li = lam[HIDC + d];
  float hr = P[(((long)b * NCH + c) * 2) * HIDC + d];
  float hi = P[(((long)b * NCH + c) * 2 + 1) * HIDC + d];
  __hip_bfloat16* ur = u + ((long)(b * L_SZ + c * LCH)) * NCOL + d;
  __hip_bfloat16* ui = ur + HIDC;
  const float* mrow = mask + b * L_SZ + c * LCH;
  for (int l = 0; l < LCH; l++) {
    float xr = __bfloat162float(ur[(long)l * NCOL]);
    float xi = __bfloat162float(ui[(long)l * NCOL]);
    int gl = c * LCH + l;
    float g = (gl > 0) ? mrow[l - 1] : 0.f;
    float nr = xr + g * (lr * hr - li * hi);
    float ni = xi + g * (lr * hi + li * hr);
    hr = nr; hi = ni;
    ur[(long)l * NCOL] = __float2bfloat16(hr);
    ui[(long)l * NCOL] = __float2bfloat16(hi);
  }
}

// ---------------- LayerNorm over D=512, in place on d_out ----------------
__global__ __launch_bounds__(256) void k_ln(float* __restrict__ y,
                                            const float* __restrict__ lnw,
                                            const float* __restrict__ lnb) {
  int row = blockIdx.x, t = threadIdx.x;
  float2 v = ((const float2*)(y + (long)row * DM))[t];
  float s = v.x + v.y;
  float q = v.x * v.x + v.y * v.y;
  for (int off = 32; off; off >>= 1) { s += __shfl_down(s, off); q += __shfl_down(q, off); }
  __shared__ float ss[4], sq[4];
  int w = t >> 6, lane = t & 63;
  if (lane == 0) { ss[w] = s; sq[w] = q; }
  __syncthreads();
  if (t == 0) {
    float S = ss[0] + ss[1] + ss[2] + ss[3];
    float Q = sq[0] + sq[1] + sq[2] + sq[3];
    float mu = S / (float)DM;
    float var = Q / (float)DM - mu * mu;
    ss[0] = mu; sq[0] = rsqrtf(var + 1e-5f);
  }
  __syncthreads();
  float mu = ss[0], rstd = sq[0];
  float2 o;
  o.x = (v.x - mu) * rstd * lnw[2 * t]     + lnb[2 * t];
  o.y = (v.y - mu) * rstd * lnw[2 * t + 1] + lnb[2 * t + 1];
  ((float2*)(y + (long)row * DM))[t] = o;
}

// ---------------- launch ----------------
extern "C" void kernel_launch(void* const* d_in, const int* in_sizes, int n_in,
                              void* d_out, int out_size, void* d_ws, size_t ws_size,
                              hipStream_t stream) {
  (void)in_sizes; (void)n_in; (void)out_size; (void)ws_size;
  const float* x         = (const float*)d_in[0];
  const float* mask      = (const float*)d_in[1];
  const float* nu_log    = (const float*)d_in[2];
  const float* theta_log = (const float*)d_in[3];
  const float* gamma_log = (const float*)d_in[4];
  const float* W_in_r    = (const float*)d_in[5];
  const float* W_in_i    = (const float*)d_in[6];
  const float* b_in_r    = (const float*)d_in[7];
  const float* b_in_i    = (const float*)d_in[8];
  const float* W_out_r   = (const float*)d_in[9];
  const float* W_out_i   = (const float*)d_in[10];
  const float* b_out_r   = (const float*)d_in[11];
  const float* ln_w      = (const float*)d_in[13];
  const float* ln_b      = (const float*)d_in[14];

  char* ws = (char*)d_ws;
  unsigned short* ubuf = (unsigned short*)(ws);              // 67,108,864
  unsigned short* xb   = (unsigned short*)(ws + 67108864);   // 16,777,216
  unsigned short* W1b  = (unsigned short*)(ws + 83886080);   // 2,097,152
  unsigned short* W2b  = (unsigned short*)(ws + 85983232);   // 2,097,152
  float* b1   = (float*)(ws + 88080384);                     // 8,192
  float* lam  = (float*)(ws + 88088576);                     // 8,192
  float* Ebuf = (float*)(ws + 88096768);                     // 1,048,576
  float* Pbuf = (float*)(ws + 89145344);                     // 1,048,576

  const int LDS1 = 3 * (256 + 128) * 32 * 2;                 // 73728 (MF=8)
  const int LDS2 = 3 * (128 + 128) * 32 * 2;                 // 49152 (MF=4)
  hipFuncSetAttribute((const void*)gemm_pipe<8, 1, 0, 4>,
                      hipFuncAttributeMaxDynamicSharedMemorySize, LDS1);
  hipFuncSetAttribute((const void*)gemm_pipe<4, 0, 1, 2>,
                      hipFuncAttributeMaxDynamicSharedMemorySize, LDS2);

  k_cvt_x  <<<8192, 256, 0, stream>>>(x, xb);
  k_prep_w1<<<4096, 256, 0, stream>>>(W_in_r, W_in_i, b_in_r, b_in_i, gamma_log, W1b, b1);
  k_prep_w2<<<4096, 256, 0, stream>>>(W_out_r, W_out_i, W2b);
  k_prep_lam<<<4, 256, 0, stream>>>(nu_log, theta_log, lam);

  // GEMM1: u = xb @ W1b^T + b1 -> bf16 ubuf; BM=256, grid 64*16 = 1024 WGs
  gemm_pipe<8, 1, 0, 4><<<1024, 256, LDS1, stream>>>(
      xb, W1b, (void*)ubuf, b1, nullptr, NROW, NCOL, DM);

  // chunked linear-recurrence scan, in place on ubuf
  k_scan_local<<<dim3(B_SZ, NCH, HIDC / 256), 256, 0, stream>>>(
      (const __hip_bfloat16*)ubuf, lam, mask, Ebuf);
  k_scan_carry<<<32, 256, 0, stream>>>(Ebuf, lam, Pbuf);
  k_scan_final<<<dim3(B_SZ, NCH, HIDC / 256), 256, 0, stream>>>(
      (__hip_bfloat16*)ubuf, lam, mask, Pbuf);

  // GEMM2: out = h @ W2b^T + b_out_r + xb -> fp32 d_out; BM=128, grid 128*4 = 512 WGs
  gemm_pipe<4, 0, 1, 2><<<512, 256, LDS2, stream>>>(
      ubuf, W2b, d_out, b_out_r, xb, NROW, DM, NCOL);

  // LayerNorm in place on d_out
  k_ln<<<NROW, 256, 0, stream>>>((float*)d_out, ln_w, ln_b);
}

// Round 5
// 192.442 us; speedup vs baseline: 1.1227x; 1.0029x over previous
//
#include <hip/hip_runtime.h>
#include <hip/hip_bf16.h>

// Problem constants
#define B_SZ 8
#define L_SZ 2048
#define DM   512
#define HIDC 1024            // complex hidden channels
#define NROW (B_SZ*L_SZ)     // 16384
#define NCOL (2*HIDC)        // 2048 (re || im)
#define LCH  128             // scan chunk length
#define NCH  (L_SZ/LCH)      // 16 chunks

typedef __attribute__((ext_vector_type(8))) short bf16x8;
typedef __attribute__((ext_vector_type(4))) float f32x4;

typedef __attribute__((address_space(1))) const void gvoid_t;
typedef __attribute__((address_space(3))) void lvoid_t;

__device__ __forceinline__ void gload_lds16(const void* g, void* l) {
  __builtin_amdgcn_global_load_lds((gvoid_t*)g, (lvoid_t*)l, 16, 0, 0);
}

__device__ __forceinline__ unsigned short f2bf(float v) {
  return __builtin_bit_cast(unsigned short, __float2bfloat16(v));
}
__device__ __forceinline__ float bf2f(unsigned short u) {
  return __bfloat162float(__builtin_bit_cast(__hip_bfloat16, u));
}

// ---------------- prep kernels ----------------
__global__ void k_cvt_x(const float* __restrict__ x, unsigned short* __restrict__ xb) {
  long i = (long)blockIdx.x * 256 + threadIdx.x;
  float4 v = ((const float4*)x)[i];
  ushort4 o;
  o.x = f2bf(v.x); o.y = f2bf(v.y); o.z = f2bf(v.z); o.w = f2bf(v.w);
  ((ushort4*)xb)[i] = o;
}

__global__ void k_prep_w1(const float* __restrict__ Wr, const float* __restrict__ Wi,
                          const float* __restrict__ br, const float* __restrict__ bi,
                          const float* __restrict__ gamma_log,
                          unsigned short* __restrict__ W1b, float* __restrict__ b1) {
  long idx = (long)blockIdx.x * 256 + threadIdx.x; // 2048*512
  int n = (int)(idx >> 9), k = (int)(idx & 511);
  int d = n & (HIDC - 1);
  float g = __expf(gamma_log[d]);
  float w = (n < HIDC) ? Wr[(long)d * DM + k] : Wi[(long)d * DM + k];
  W1b[idx] = f2bf(g * w);
  if (k == 0) b1[n] = g * ((n < HIDC) ? br[d] : bi[d]);
}

__global__ void k_prep_w2(const float* __restrict__ Wor, const float* __restrict__ Woi,
                          unsigned short* __restrict__ W2b) {
  long idx = (long)blockIdx.x * 256 + threadIdx.x; // 512*2048
  int e = (int)(idx >> 11), k = (int)(idx & 2047);
  float w = (k < HIDC) ? Wor[(long)e * HIDC + k] : -Woi[(long)e * HIDC + (k - HIDC)];
  W2b[idx] = f2bf(w);
}

__global__ void k_prep_lam(const float* __restrict__ nu_log, const float* __restrict__ theta_log,
                           float* __restrict__ lam) {
  int d = blockIdx.x * 256 + threadIdx.x;
  if (d >= HIDC) return;
  float nu = __expf(nu_log[d]);
  float th = __expf(theta_log[d]);
  float mag = __expf(-nu);
  lam[d]        = mag * cosf(th);
  lam[HIDC + d] = mag * sinf(th);
}

// ---------------- pipelined bf16 MFMA GEMM (v5) ----------------
// C[M][N] = A[M][K]*Bw[N][K]^T (+bias[col]) (+bf16 resid).
// BM = MF*32, BN = 128, BK = 32. 256 threads = 4 waves (2M x 2N); per-wave
// MF x 4 frags of 16x16x32. Triple-buffered LDS -> 2 blocks/CU.
// Depth-2 prefetch; in-loop wait = counted vmcnt(LT).
// T2 swizzle for 64B rows: bank space (128B) spans TWO rows, quad index =
// (row&1)*4 + slot. slot' = slot ^ ((row>>1)&3) makes quad enumerate all 8
// over 8 consecutive rows at fixed lq -> 2-way (free). Applied as the same
// involution on the pre-swizzled global source (linear gload_lds dest) and
// the ds_read address. (R4's slot^(row&3) was 4-way: quad ignored row&1.)
//
// Race ledger (same skeleton as R1/R3/R4, all passed):
//  - STAGE(t+2) overwrites buf((t-1)%3); tile t-1's ds_reads completed
//    (lgkm-waited before MFMA consumers) before the barrier ending iter t-1.
//  - end of iter t: outstanding = stage(t+1)[LT] + stage(t+2)[LT iff issued].
//    vmcnt(LT) (or 0 when none issued) => stage(t+1) landed; s_barrier
//    publishes it.
template<int MF, int OUT_BF16, int HAS_RESID, int LGY>
__global__ __launch_bounds__(256, 2)
void gemm_pipe(const unsigned short* __restrict__ A, const unsigned short* __restrict__ Bw,
               void* __restrict__ C, const float* __restrict__ bias,
               const unsigned short* __restrict__ resid, int M, int N, int K) {
  constexpr int BM     = MF * 32;
  constexpr int AUNITS = MF / 2;        // 4KB staging units per A tile
  constexpr int LT     = AUNITS + 2;    // gloads per stage
  constexpr int ABUF   = BM * 32;       // ushorts per A buffer
  constexpr int BBUF   = 128 * 32;

  extern __shared__ unsigned short lds[];
  unsigned short* As = lds;             // 3 * ABUF
  unsigned short* Bs = lds + 3 * ABUF;  // 3 * BBUF

  const int tid  = threadIdx.x;
  const int w    = tid >> 6, lane = tid & 63;
  const int wr   = w >> 1,   wc   = w & 1;    // 2 x 2 wave grid
  const int fr   = lane & 15, lq  = lane >> 4;

  // XCD 2-D blocking (blockIdx.x % 8 assumed = XCD; perf heuristic only)
  const int gx   = M / BM;
  const int xcd  = blockIdx.x & 7;
  const int idx  = blockIdx.x >> 3;
  const int mt   = xcd * (gx >> 3) + (idx >> LGY);
  const int nt   = idx & ((1 << LGY) - 1);
  const long m0  = (long)mt * BM;
  const long n0  = (long)nt * 128;

  // ---- staging: 64B rows, 4 threads/row; 256 thr * 16B = 64 rows per unit ----
  // source slot = dest slot ^ ((row>>1)&3)  [dest = linear tid*16B]
  const int srow  = tid >> 2;                       // 0..63
  const int gslot = (tid & 3) ^ ((tid >> 3) & 3);   // (srow>>1)&3 = (tid>>3)&3
  const unsigned short* Agp = A  + (m0 + srow) * (long)K + gslot * 8;
  const unsigned short* Bgp = Bw + (n0 + srow) * (long)K + gslot * 8;
  const int ldst = tid * 8;

#define STAGE(t, b) {                                                        \
    long ko = (long)(t) * 32;                                                \
    _Pragma("unroll")                                                        \
    for (int u = 0; u < AUNITS; u++)                                         \
      gload_lds16(Agp + ko + (long)(u * 64) * K,                             \
                  &As[(b) * ABUF + u * 2048 + ldst]);                        \
    gload_lds16(Bgp + ko,                  &Bs[(b) * BBUF +        ldst]);   \
    gload_lds16(Bgp + ko + (long)64 * K,   &Bs[(b) * BBUF + 2048 + ldst]); }

  // ---- ds_read: row r wants global slot lq, stored at slot lq^((r>>1)&3);
  //      r = 16-aligned base + fr  =>  (r>>1)&3 = (fr>>1)&3 ----
  const int sx = (lq ^ ((fr >> 1) & 3)) << 3;

  f32x4 acc[MF][4] = {};
  const int NT = K >> 5;

  STAGE(0, 0);
  STAGE(1, 1);
  if constexpr (LT == 6) asm volatile("s_waitcnt vmcnt(6)" ::: "memory");
  else                   asm volatile("s_waitcnt vmcnt(4)" ::: "memory");
  __builtin_amdgcn_s_barrier();
  __builtin_amdgcn_sched_barrier(0);

  int cb = 0, bt2 = 2;
  for (int t = 0; t < NT; ++t) {
    if (t + 2 < NT) STAGE(t + 2, bt2);

    const unsigned short* Ab = As + cb * ABUF;
    const unsigned short* Bb = Bs + cb * BBUF;
    bf16x8 fa[MF], fb[4];
#pragma unroll
    for (int m = 0; m < MF; m++)
      fa[m] = *(const bf16x8*)&Ab[(wr * (MF * 16) + m * 16 + fr) * 32 + sx];
#pragma unroll
    for (int n = 0; n < 4; n++)
      fb[n] = *(const bf16x8*)&Bb[(wc * 64 + n * 16 + fr) * 32 + sx];
    __builtin_amdgcn_s_setprio(1);
#pragma unroll
    for (int m = 0; m < MF; m++)
#pragma unroll
      for (int n = 0; n < 4; n++)
        acc[m][n] = __builtin_amdgcn_mfma_f32_16x16x32_bf16(fa[m], fb[n], acc[m][n], 0, 0, 0);
    __builtin_amdgcn_s_setprio(0);

    if (t < NT - 1) {
      if (t + 2 < NT) {
        if constexpr (LT == 6) asm volatile("s_waitcnt vmcnt(6)" ::: "memory");
        else                   asm volatile("s_waitcnt vmcnt(4)" ::: "memory");
      } else {
        asm volatile("s_waitcnt vmcnt(0)" ::: "memory");
      }
      __builtin_amdgcn_s_barrier();
      __builtin_amdgcn_sched_barrier(0);
    }
    cb  = (cb  == 2) ? 0 : cb + 1;
    bt2 = (bt2 == 2) ? 0 : bt2 + 1;
  }
#undef STAGE

  // epilogue: C/D layout col=lane&15, row=(lane>>4)*4+r (m89-verified)
  const int cr0 = lq * 4, cc = fr;
#pragma unroll
  for (int m = 0; m < MF; m++) {
#pragma unroll
    for (int n = 0; n < 4; n++) {
      long col = n0 + wc * 64 + n * 16 + cc;
      float bv = bias[col];
#pragma unroll
      for (int r = 0; r < 4; r++) {
        long row = m0 + wr * (MF * 16) + m * 16 + cr0 + r;
        float v = acc[m][n][r] + bv;
        if (HAS_RESID) v += bf2f(resid[row * (long)N + col]);
        if (OUT_BF16)
          ((unsigned short*)C)[row * (long)N + col] = f2bf(v);
        else
          ((float*)C)[row * (long)N + col] = v;
      }
    }
  }
}

// ---------------- chunked scan (3 passes), in-place on ubuf (bf16) ----------------
__global__ void k_scan_local(const __hip_bfloat16* __restrict__ u,
                             const float* __restrict__ lam,
                             const float* __restrict__ mask,
                             float* __restrict__ E) {
  int b = blockIdx.x, c = blockIdx.y, dg = blockIdx.z, t = threadIdx.x;
  int d = dg * 256 + t;
  float lr = lam[d], li = lam[HIDC + d];
  float hr = 0.f, hi = 0.f;
  const __hip_bfloat16* ur = u + ((long)(b * L_SZ + c * LCH)) * NCOL + d;
  const __hip_bfloat16* ui = ur + HIDC;
  const float* mrow = mask + b * L_SZ + c * LCH;
  for (int l = 0; l < LCH; l++) {
    float xr = __bfloat162float(ur[(long)l * NCOL]);
    float xi = __bfloat162float(ui[(long)l * NCOL]);
    float g = (l > 0) ? mrow[l - 1] : 0.f;
    float nr = xr + g * (lr * hr - li * hi);
    float ni = xi + g * (lr * hi + li * hr);
    hr = nr; hi = ni;
  }
  E[(((long)b * NCH + c) * 2) * HIDC + d]     = hr;
  E[(((long)b * NCH + c) * 2 + 1) * HIDC + d] = hi;
}

__global__ void k_scan_carry(const float* __restrict__ E, const float* __restrict__ lam,
                             float* __restrict__ P) {
  int idx = blockIdx.x * 256 + threadIdx.x;   // 8192 = B * HIDC
  int b = idx >> 10, d = idx & (HIDC - 1);
  float lr = lam[d], li = lam[HIDC + d];
  float ar = lr, ai = li;                     // lam^128 via 7 squarings
  for (int s = 0; s < 7; s++) { float nr = ar * ar - ai * ai; float ni = 2.f * ar * ai; ar = nr; ai = ni; }
  float pr = 0.f, pi = 0.f;
  for (int c = 0; c < NCH; c++) {
    P[(((long)b * NCH + c) * 2) * HIDC + d]     = pr;
    P[(((long)b * NCH + c) * 2 + 1) * HIDC + d] = pi;
    float er = E[(((long)b * NCH + c) * 2) * HIDC + d];
    float ei = E[(((long)b * NCH + c) * 2 + 1) * HIDC + d];
    float nr = er + ar * pr - ai * pi;
    float ni = ei + ar * pi + ai * pr;
    pr = nr; pi = ni;
  }
}

__global__ void k_scan_final(__hip_bfloat16* __restrict__ u,
                             const float* __restrict__ lam,
                             const float* __restrict__ mask,
                             const float* __restrict__ P) {
  int b = blockIdx.x, c = blockIdx.y, dg = blockIdx.z, t = threadIdx.x;
  int d = dg * 256 + t;
  float lr = lam[d], li = lam[HIDC + d];
  float hr = P[(((long)b * NCH + c) * 2) * HIDC + d];
  float hi = P[(((long)b * NCH + c) * 2 + 1) * HIDC + d];
  __hip_bfloat16* ur = u + ((long)(b * L_SZ + c * LCH)) * NCOL + d;
  __hip_bfloat16* ui = ur + HIDC;
  const float* mrow = mask + b * L_SZ + c * LCH;
  for (int l = 0; l < LCH; l++) {
    float xr = __bfloat162float(ur[(long)l * NCOL]);
    float xi = __bfloat162float(ui[(long)l * NCOL]);
    int gl = c * LCH + l;
    float g = (gl > 0) ? mrow[l - 1] : 0.f;
    float nr = xr + g * (lr * hr - li * hi);
    float ni = xi + g * (lr * hi + li * hr);
    hr = nr; hi = ni;
    ur[(long)l * NCOL] = __float2bfloat16(hr);
    ui[(long)l * NCOL] = __float2bfloat16(hi);
  }
}

// ---------------- LayerNorm over D=512, in place on d_out ----------------
__global__ __launch_bounds__(256) void k_ln(float* __restrict__ y,
                                            const float* __restrict__ lnw,
                                            const float* __restrict__ lnb) {
  int row = blockIdx.x, t = threadIdx.x;
  float2 v = ((const float2*)(y + (long)row * DM))[t];
  float s = v.x + v.y;
  float q = v.x * v.x + v.y * v.y;
  for (int off = 32; off; off >>= 1) { s += __shfl_down(s, off); q += __shfl_down(q, off); }
  __shared__ float ss[4], sq[4];
  int w = t >> 6, lane = t & 63;
  if (lane == 0) { ss[w] = s; sq[w] = q; }
  __syncthreads();
  if (t == 0) {
    float S = ss[0] + ss[1] + ss[2] + ss[3];
    float Q = sq[0] + sq[1] + sq[2] + sq[3];
    float mu = S / (float)DM;
    float var = Q / (float)DM - mu * mu;
    ss[0] = mu; sq[0] = rsqrtf(var + 1e-5f);
  }
  __syncthreads();
  float mu = ss[0], rstd = sq[0];
  float2 o;
  o.x = (v.x - mu) * rstd * lnw[2 * t]     + lnb[2 * t];
  o.y = (v.y - mu) * rstd * lnw[2 * t + 1] + lnb[2 * t + 1];
  ((float2*)(y + (long)row * DM))[t] = o;
}

// ---------------- launch ----------------
extern "C" void kernel_launch(void* const* d_in, const int* in_sizes, int n_in,
                              void* d_out, int out_size, void* d_ws, size_t ws_size,
                              hipStream_t stream) {
  (void)in_sizes; (void)n_in; (void)out_size; (void)ws_size;
  const float* x         = (const float*)d_in[0];
  const float* mask      = (const float*)d_in[1];
  const float* nu_log    = (const float*)d_in[2];
  const float* theta_log = (const float*)d_in[3];
  const float* gamma_log = (const float*)d_in[4];
  const float* W_in_r    = (const float*)d_in[5];
  const float* W_in_i    = (const float*)d_in[6];
  const float* b_in_r    = (const float*)d_in[7];
  const float* b_in_i    = (const float*)d_in[8];
  const float* W_out_r   = (const float*)d_in[9];
  const float* W_out_i   = (const float*)d_in[10];
  const float* b_out_r   = (const float*)d_in[11];
  const float* ln_w      = (const float*)d_in[13];
  const float* ln_b      = (const float*)d_in[14];

  char* ws = (char*)d_ws;
  unsigned short* ubuf = (unsigned short*)(ws);              // 67,108,864
  unsigned short* xb   = (unsigned short*)(ws + 67108864);   // 16,777,216
  unsigned short* W1b  = (unsigned short*)(ws + 83886080);   // 2,097,152
  unsigned short* W2b  = (unsigned short*)(ws + 85983232);   // 2,097,152
  float* b1   = (float*)(ws + 88080384);                     // 8,192
  float* lam  = (float*)(ws + 88088576);                     // 8,192
  float* Ebuf = (float*)(ws + 88096768);                     // 1,048,576
  float* Pbuf = (float*)(ws + 89145344);                     // 1,048,576

  const int LDS1 = 3 * (256 + 128) * 32 * 2;                 // 73728 (MF=8)
  const int LDS2 = 3 * (128 + 128) * 32 * 2;                 // 49152 (MF=4)
  hipFuncSetAttribute((const void*)gemm_pipe<8, 1, 0, 4>,
                      hipFuncAttributeMaxDynamicSharedMemorySize, LDS1);
  hipFuncSetAttribute((const void*)gemm_pipe<4, 0, 1, 2>,
                      hipFuncAttributeMaxDynamicSharedMemorySize, LDS2);

  k_cvt_x  <<<8192, 256, 0, stream>>>(x, xb);
  k_prep_w1<<<4096, 256, 0, stream>>>(W_in_r, W_in_i, b_in_r, b_in_i, gamma_log, W1b, b1);
  k_prep_w2<<<4096, 256, 0, stream>>>(W_out_r, W_out_i, W2b);
  k_prep_lam<<<4, 256, 0, stream>>>(nu_log, theta_log, lam);

  // GEMM1: u = xb @ W1b^T + b1 -> bf16 ubuf; BM=256, grid 64*16 = 1024 WGs
  gemm_pipe<8, 1, 0, 4><<<1024, 256, LDS1, stream>>>(
      xb, W1b, (void*)ubuf, b1, nullptr, NROW, NCOL, DM);

  // chunked linear-recurrence scan, in place on ubuf
  k_scan_local<<<dim3(B_SZ, NCH, HIDC / 256), 256, 0, stream>>>(
      (const __hip_bfloat16*)ubuf, lam, mask, Ebuf);
  k_scan_carry<<<32, 256, 0, stream>>>(Ebuf, lam, Pbuf);
  k_scan_final<<<dim3(B_SZ, NCH, HIDC / 256), 256, 0, stream>>>(
      (__hip_bfloat16*)ubuf, lam, mask, Pbuf);

  // GEMM2: out = h @ W2b^T + b_out_r + xb -> fp32 d_out; BM=128, grid 128*4 = 512 WGs
  gemm_pipe<4, 0, 1, 2><<<512, 256, LDS2, stream>>>(
      ubuf, W2b, d_out, b_out_r, xb, NROW, DM, NCOL);

  // LayerNorm in place on d_out
  k_ln<<<NROW, 256, 0, stream>>>((float*)d_out, ln_w, ln_b);
}